// Round 4
// baseline (353.622 us; speedup 1.0000x reference)
//
#include <hip/hip_runtime.h>

#define Wd 1024
#define Hd 1024
#define SH 16            // output rows per block
#define ITER (SH + 6)    // input rows streamed (3-row halo each side)

__device__ __forceinline__ float2 ld2(const float* p) { return *(const float2*)p; }

__global__ __launch_bounds__(256, 6)
void lvm_f2(const float* __restrict__ x, float* __restrict__ out) {
    const int b    = blockIdx.z;
    const int row0 = blockIdx.x * SH;
    const int c0   = blockIdx.y * 512 + threadIdx.x * 2;  // 2 output cols/thread

    const float* x0 = x + (size_t)b * 3 * Hd * Wd;
    const float* x1 = x0 + (size_t)Hd * Wd;
    const float* x2 = x1 + (size_t)Hd * Wd;
    float*       ob = out + (size_t)b * Hd * Wd;

    // 5 pair-aligned float2 loads cover cols c0-4 .. c0+5 (clamped at borders)
    int cofs[5];
#pragma unroll
    for (int j = 0; j < 5; ++j) {
        int cl = c0 - 4 + 2 * j;
        cofs[j] = min(max(cl, 0), Wd - 2);
    }
    // validity of window cols c0-3 .. c0+4 (zero-pad semantics)
    bool vld0 = (c0 - 3 >= 0), vld1 = (c0 - 2 >= 0), vld2 = (c0 - 1 >= 0);
    bool vld5 = (c0 + 2 < Wd), vld6 = (c0 + 3 < Wd), vld7 = (c0 + 4 < Wd);

    float2 ring1[7], ring2[7];   // last 7 rows' horizontal 7-tap sums (s, s^2)

#pragma unroll
    for (int i = 0; i < ITER; ++i) {
        const int ri = row0 - 3 + i;             // input row (wave-uniform)
        float2 A0, A1, A2, A3, A4;               // s = ch0+ch1+ch2 (lum*3)
        if (ri >= 0 && ri < Hd) {
            const size_t rb = (size_t)ri * Wd;
            const float* p0 = x0 + rb;
            const float* p1 = x1 + rb;
            const float* p2 = x2 + rb;
            float2 a, g, c;
            a = ld2(p0 + cofs[0]); g = ld2(p1 + cofs[0]); c = ld2(p2 + cofs[0]);
            A0 = make_float2(a.x + g.x + c.x, a.y + g.y + c.y);
            a = ld2(p0 + cofs[1]); g = ld2(p1 + cofs[1]); c = ld2(p2 + cofs[1]);
            A1 = make_float2(a.x + g.x + c.x, a.y + g.y + c.y);
            a = ld2(p0 + cofs[2]); g = ld2(p1 + cofs[2]); c = ld2(p2 + cofs[2]);
            A2 = make_float2(a.x + g.x + c.x, a.y + g.y + c.y);
            a = ld2(p0 + cofs[3]); g = ld2(p1 + cofs[3]); c = ld2(p2 + cofs[3]);
            A3 = make_float2(a.x + g.x + c.x, a.y + g.y + c.y);
            a = ld2(p0 + cofs[4]); g = ld2(p1 + cofs[4]); c = ld2(p2 + cofs[4]);
            A4 = make_float2(a.x + g.x + c.x, a.y + g.y + c.y);
        } else {
            A0 = A1 = A2 = A3 = A4 = make_float2(0.f, 0.f);
        }

        // window w0..w7 = s at cols c0-3 .. c0+4 (border cols zeroed)
        float w0 = vld0 ? A0.y : 0.f;
        float w1 = vld1 ? A1.x : 0.f;
        float w2 = vld2 ? A1.y : 0.f;
        float w3 = A2.x;                 // col c0   always in-range
        float w4 = A2.y;                 // col c0+1 always in-range
        float w5 = vld5 ? A3.x : 0.f;
        float w6 = vld6 ? A3.y : 0.f;
        float w7 = vld7 ? A4.x : 0.f;

        // horizontal 7-tap sums for the 2 output cols
        float s1x = ((w0 + w1) + (w2 + w3)) + ((w4 + w5) + w6);
        float s1y = s1x - w0 + w7;
        float q0 = w0*w0, q1 = w1*w1, q2 = w2*w2, q3 = w3*w3;
        float q4 = w4*w4, q5 = w5*w5, q6 = w6*w6, q7 = w7*w7;
        float s2x = ((q0 + q1) + (q2 + q3)) + ((q4 + q5) + q6);
        float s2y = s2x - q0 + q7;

        ring1[i % 7] = make_float2(s1x, s1y);
        ring2[i % 7] = make_float2(s2x, s2y);

        if (i >= 6) {                    // emit output row row0 + i - 6
            float2 t1 = ring1[0], t2 = ring2[0];
#pragma unroll
            for (int k = 1; k < 7; ++k) {
                t1.x += ring1[k].x; t1.y += ring1[k].y;
                t2.x += ring2[k].x; t2.y += ring2[k].y;
            }
            // lum = s/3: mean = sum(s)/147, sqr_mean = sum(s^2)/441
            const float inv1 = 1.f / 147.f;
            const float inv2 = 1.f / 441.f;
            float mx = t1.x * inv1, my = t1.y * inv1;
            float2 r;
            r.x = t2.x * inv2 - mx * mx;
            r.y = t2.y * inv2 - my * my;
            const int ro = row0 + i - 6;
            *(float2*)(ob + (size_t)ro * Wd + c0) = r;
        }
    }
}

extern "C" void kernel_launch(void* const* d_in, const int* in_sizes, int n_in,
                              void* d_out, int out_size, void* d_ws, size_t ws_size,
                              hipStream_t stream) {
    const float* x = (const float*)d_in[0];
    float* out = (float*)d_out;
    dim3 grid(Hd / SH, 2, 16);   // 64 row-strips x 2 col-halves x 16 batches = 2048 blocks
    lvm_f2<<<grid, dim3(256), 0, stream>>>(x, out);
}

// Round 6
// 303.359 us; speedup vs baseline: 1.1657x; 1.1657x over previous
//
#include <hip/hip_runtime.h>

#define Wd 1024
#define Hd 1024
#define SH 16            // output rows per block
#define ITER (SH + 6)    // input rows streamed (3-row halo each side)

typedef float nfloat4 __attribute__((ext_vector_type(4)));  // native vec for nontemporal store

// CK-style LDS-only barrier: waits lgkmcnt(0) but leaves global loads
// (vmcnt) in flight across the barrier -> prefetch survives the sync.
__device__ __forceinline__ void sync_lds() {
    asm volatile("s_waitcnt lgkmcnt(0)\n\ts_barrier" ::: "memory");
}

__global__ __launch_bounds__(256, 4)
void lvm_pipe(const float* __restrict__ x, float* __restrict__ out) {
    // double-buffered (3*lum) row: L[buf][4+c] = sum of 3 channels at col c
    __shared__ __align__(16) float L[2][Wd + 8];

    const int b    = blockIdx.y;
    const int row0 = blockIdx.x * SH;
    const int tid  = threadIdx.x;
    const int c0   = tid * 4;

    const float* x0 = x + (size_t)b * 3 * Hd * Wd;
    const float* x1 = x0 + (size_t)Hd * Wd;
    const float* x2 = x1 + (size_t)Hd * Wd;
    float*       ob = out + (size_t)b * Hd * Wd;

    if (tid < 4) {   // zero horizontal halo columns once (never rewritten)
        L[0][tid] = 0.f; L[0][Wd + 4 + tid] = 0.f;
        L[1][tid] = 0.f; L[1][Wd + 4 + tid] = 0.f;
    }

    float4 ring1[7], ring2[7];
    float4 t1 = make_float4(0.f, 0.f, 0.f, 0.f);
    float4 t2 = make_float4(0.f, 0.f, 0.f, 0.f);

    // prologue: issue prefetch of first input row (ri = row0-3)
    float4 pa, pg, pc;
    bool pv;
    {
        const int ri = row0 - 3;
        pv = (ri >= 0) && (ri < Hd);
        if (pv) {
            const size_t o = (size_t)ri * Wd + c0;
            pa = *(const float4*)(x0 + o);
            pg = *(const float4*)(x1 + o);
            pc = *(const float4*)(x2 + o);
        }
    }

#pragma unroll
    for (int i = 0; i < ITER; ++i) {
        // step 1: combine prefetched row i (waits vmcnt), write to LDS
        float4 s;
        if (pv) {
            s.x = pa.x + pg.x + pc.x;
            s.y = pa.y + pg.y + pc.y;
            s.z = pa.z + pg.z + pc.z;
            s.w = pa.w + pg.w + pc.w;
        } else {
            s = make_float4(0.f, 0.f, 0.f, 0.f);
        }
        float* Lr = L[i & 1];
        *(float4*)(Lr + 4 + c0) = s;

        // step 2: issue prefetch for row i+1 (stays in flight across barrier)
        if (i + 1 < ITER) {
            const int ri = row0 - 3 + (i + 1);
            pv = (ri >= 0) && (ri < Hd);
            if (pv) {
                const size_t o = (size_t)ri * Wd + c0;
                pa = *(const float4*)(x0 + o);
                pg = *(const float4*)(x1 + o);
                pc = *(const float4*)(x2 + o);
            }
        }

        // step 3: LDS-only barrier (vmcnt prefetch NOT drained)
        sync_lds();

        // step 4: horizontal window from LDS, sums, vertical running totals
        float4 va = *(const float4*)(Lr + c0);       // cols c0-4..c0-1
        float4 vb = *(const float4*)(Lr + c0 + 4);   // cols c0  ..c0+3
        float4 vc = *(const float4*)(Lr + c0 + 8);   // cols c0+4..c0+7
        const float v1 = va.y, v2 = va.z, v3 = va.w;
        const float v4 = vb.x, v5 = vb.y, v6 = vb.z, v7 = vb.w;
        const float v8 = vc.x, v9 = vc.y, v10 = vc.z;

        float s1a = ((v1 + v2) + (v3 + v4)) + ((v5 + v6) + v7);
        float s1b = s1a - v1 + v8;
        float s1c = s1b - v2 + v9;
        float s1d = s1c - v3 + v10;

        float q1 = v1*v1, q2 = v2*v2, q3 = v3*v3, q4 = v4*v4, q5 = v5*v5;
        float q6 = v6*v6, q7 = v7*v7, q8 = v8*v8, q9 = v9*v9, q10 = v10*v10;
        float s2a = ((q1 + q2) + (q3 + q4)) + ((q5 + q6) + q7);
        float s2b = s2a - q1 + q8;
        float s2c = s2b - q2 + q9;
        float s2d = s2c - q3 + q10;

        float4 n1 = make_float4(s1a, s1b, s1c, s1d);
        float4 n2 = make_float4(s2a, s2b, s2c, s2d);

        t1.x += n1.x; t1.y += n1.y; t1.z += n1.z; t1.w += n1.w;
        t2.x += n2.x; t2.y += n2.y; t2.z += n2.z; t2.w += n2.w;
        if (i >= 7) {
            float4 o1 = ring1[i % 7], o2 = ring2[i % 7];
            t1.x -= o1.x; t1.y -= o1.y; t1.z -= o1.z; t1.w -= o1.w;
            t2.x -= o2.x; t2.y -= o2.y; t2.z -= o2.z; t2.w -= o2.w;
        }
        ring1[i % 7] = n1;
        ring2[i % 7] = n2;

        if (i >= 6) {   // emit output row row0 + i - 6
            // s = 3*lum  ->  mean = t1/147, sqr_mean = t2/441
            const float inv1 = 1.f / 147.f;
            const float inv2 = 1.f / 441.f;
            float mx = t1.x * inv1, my = t1.y * inv1;
            float mz = t1.z * inv1, mw = t1.w * inv1;
            nfloat4 r;
            r.x = t2.x * inv2 - mx * mx;
            r.y = t2.y * inv2 - my * my;
            r.z = t2.z * inv2 - mz * mz;
            r.w = t2.w * inv2 - mw * mw;
            const int ro = row0 + i - 6;
            __builtin_nontemporal_store(r, (nfloat4*)(ob + (size_t)ro * Wd + c0));
        }
    }
}

extern "C" void kernel_launch(void* const* d_in, const int* in_sizes, int n_in,
                              void* d_out, int out_size, void* d_ws, size_t ws_size,
                              hipStream_t stream) {
    const float* x = (const float*)d_in[0];
    float* out = (float*)d_out;
    dim3 grid(Hd / SH, 16);   // 64 row-strips x 16 batches = 1024 blocks (4/CU)
    lvm_pipe<<<grid, dim3(256), 0, stream>>>(x, out);
}